// Round 1
// baseline (282.426 us; speedup 1.0000x reference)
//
#include <hip/hip_runtime.h>
#include <math.h>

// Problem shape (fixed by the reference setup_inputs):
#define B_DIM  8
#define T_DIM  256
#define U_DIM  100
#define U1_DIM 101
#define V_DIM  128

__device__ __forceinline__ float logadd(float a, float b) {
    float m = fmaxf(a, b);
    if (m == -INFINITY) return -INFINITY;   // both -inf -> avoid NaN
    return m + log1pf(__expf(fminf(a, b) - m));
}

// Kernel 1: log-softmax over V=128 per (b,t,u) row; emit blank lp and label lp.
// One 64-lane wave per row; each lane holds float2 (elements 2*lane, 2*lane+1).
__global__ __launch_bounds__(256) void lsm_kernel(
    const float* __restrict__ acts, const int* __restrict__ labels,
    float* __restrict__ blank, float* __restrict__ emit, int nrows)
{
    int wid  = (blockIdx.x << 2) + (threadIdx.x >> 6);
    if (wid >= nrows) return;
    int lane = threadIdx.x & 63;

    const float* row = acts + (size_t)wid * V_DIM;
    float2 x = *reinterpret_cast<const float2*>(row + 2 * lane);

    float m = fmaxf(x.x, x.y);
    #pragma unroll
    for (int off = 32; off; off >>= 1) m = fmaxf(m, __shfl_xor(m, off));
    float s = __expf(x.x - m) + __expf(x.y - m);
    #pragma unroll
    for (int off = 32; off; off >>= 1) s += __shfl_xor(s, off);
    float lse = m + __logf(s);

    int u  = wid % U1_DIM;
    int bt = wid / U1_DIM;          // b*T + t
    int b  = bt / T_DIM;

    if (lane == 0) blank[wid] = x.x - lse;         // BLANK = 0 -> element 0
    if (u < U_DIM) {
        int lab = labels[b * U_DIM + u];           // 0..127
        if (lane == (lab >> 1)) {
            float v = (lab & 1) ? x.y : x.x;
            emit[bt * U_DIM + u] = v - lse;
        }
    }
}

// Kernel 2: anti-diagonal DP per batch. 8 blocks x 128 threads.
// alpha[t,u] = logadd(alpha[t-1,u]+blank[t-1,u], alpha[t,u-1]+emit[t,u-1])
__global__ __launch_bounds__(128) void dp_kernel(
    const float* __restrict__ blank, const float* __restrict__ emit,
    const int* __restrict__ act_lens, const int* __restrict__ label_lens,
    float* __restrict__ loglike)
{
    int b = blockIdx.x;
    int u = threadIdx.x;            // 0..127 (valid cells: u < U1)
    const float* bl = blank + (size_t)b * T_DIM * U1_DIM;
    const float* em = emit  + (size_t)b * T_DIM * U_DIM;
    int tl = act_lens[b] - 1;
    int ul = label_lens[b];

    __shared__ float diag[2][128];
    diag[0][u] = (u == 0) ? 0.0f : -INFINITY;   // d = 0: alpha[0,0] = 0
    diag[1][u] = -INFINITY;
    __syncthreads();

    const float NEG = -INFINITY;
    // Prefetch operands for d = 1
    float blA = NEG, emC = NEG;
    {
        int t = 1 - u;
        bool valid = (u < U1_DIM) && (t >= 0) && (t < T_DIM);
        if (valid && t > 0) blA = bl[(t - 1) * U1_DIM + u];
        if (valid && u > 0) emC = em[t * U_DIM + (u - 1)];
    }

    const int DMAX = (T_DIM - 1) + U_DIM;   // 355
    for (int d = 1; d <= DMAX; ++d) {
        // Prefetch operands for d+1 (loads overlap this iteration's compute+barrier)
        float blA_n = NEG, emC_n = NEG;
        {
            int t = d + 1 - u;
            bool valid = (u < U1_DIM) && (t >= 0) && (t < T_DIM);
            if (valid && t > 0) blA_n = bl[(t - 1) * U1_DIM + u];
            if (valid && u > 0) emC_n = em[t * U_DIM + (u - 1)];
        }

        int t = d - u;
        bool valid = (u < U1_DIM) && (t >= 0) && (t < T_DIM);
        float val = NEG;
        const float* prev = diag[(d - 1) & 1];
        if (valid) {
            float pa = prev[u];
            float pc = (u > 0) ? prev[u - 1] : NEG;
            val = logadd(pa + blA, pc + emC);
            if (t == tl && u == ul) loglike[b] = val + bl[t * U1_DIM + u];
        }
        diag[d & 1][u] = val;
        __syncthreads();
        blA = blA_n; emC = emC_n;
    }
}

// Kernel 3: deterministic fixed-order reduction of the 8 per-batch loglikes.
__global__ void finalize_kernel(const float* __restrict__ loglike, float* __restrict__ out) {
    if (threadIdx.x == 0 && blockIdx.x == 0) {
        float s = 0.0f;
        #pragma unroll
        for (int i = 0; i < B_DIM; ++i) s += loglike[i];
        out[0] = -s / (float)B_DIM;
    }
}

extern "C" void kernel_launch(void* const* d_in, const int* in_sizes, int n_in,
                              void* d_out, int out_size, void* d_ws, size_t ws_size,
                              hipStream_t stream) {
    const float* acts      = (const float*)d_in[0];
    const int*   labels    = (const int*)d_in[1];
    const int*   act_lens  = (const int*)d_in[2];
    const int*   label_lens= (const int*)d_in[3];

    float* ws      = (float*)d_ws;
    float* blank   = ws;                                   // B*T*U1 floats
    float* emit    = blank + B_DIM * T_DIM * U1_DIM;       // B*T*U floats
    float* loglike = emit  + B_DIM * T_DIM * U_DIM;        // B floats

    int nrows   = B_DIM * T_DIM * U1_DIM;                  // 206,848
    int nblocks = (nrows + 3) / 4;                         // 4 waves per 256-thr block

    lsm_kernel<<<nblocks, 256, 0, stream>>>(acts, labels, blank, emit, nrows);
    dp_kernel<<<B_DIM, 128, 0, stream>>>(blank, emit, act_lens, label_lens, loglike);
    finalize_kernel<<<1, 64, 0, stream>>>(loglike, (float*)d_out);
}

// Round 2
// 110.865 us; speedup vs baseline: 2.5475x; 2.5475x over previous
//
#include <hip/hip_runtime.h>
#include <math.h>

// Problem shape (fixed by the reference setup_inputs):
#define B_DIM  8
#define T_DIM  256
#define U_DIM  100
#define U1_DIM 101
#define V_DIM  128

// Diagonal-major operand arrays: [b][d][u], d = t+u(+1), stride SD.
#define SD     104
#define DROWS  376   // max written d = 356; max prefetched row = 368

__device__ __forceinline__ float logadd(float a, float b) {
    float m = fmaxf(a, b);
    if (m == -INFINITY) return -INFINITY;   // both -inf -> avoid NaN
    float n = fminf(a, b);
    return m + __logf(1.0f + __expf(n - m));
}

// Kernel 1: log-softmax over V=128 per (b,t,u) row.
// One 32-lane half-wave per row, float4 per lane (16B/lane, 1KB/wave-load).
// Writes blank (row layout, for final term) + bl_diag/em_diag (diagonal layout).
__global__ __launch_bounds__(256) void lsm_kernel(
    const float* __restrict__ acts, const int* __restrict__ labels,
    float* __restrict__ blank_row, float* __restrict__ bl_diag,
    float* __restrict__ em_diag, int nrows)
{
    int rid = blockIdx.x * 8 + (threadIdx.x >> 5);   // 8 rows per 256-thr block
    if (rid >= nrows) return;
    int hl = threadIdx.x & 31;                        // lane within 32-half

    const float* row = acts + (size_t)rid * V_DIM;
    float4 x = *reinterpret_cast<const float4*>(row + 4 * hl);

    float m = fmaxf(fmaxf(x.x, x.y), fmaxf(x.z, x.w));
    #pragma unroll
    for (int off = 16; off; off >>= 1) m = fmaxf(m, __shfl_xor(m, off));
    float s = __expf(x.x - m) + __expf(x.y - m) + __expf(x.z - m) + __expf(x.w - m);
    #pragma unroll
    for (int off = 16; off; off >>= 1) s += __shfl_xor(s, off);
    float lse = m + __logf(s);

    int u  = rid % U1_DIM;
    int bt = rid / U1_DIM;          // b*T + t
    int b  = bt / T_DIM;
    int t  = bt - b * T_DIM;

    if (hl == 0) {
        float lpb = x.x - lse;                       // BLANK = vocab element 0
        blank_row[rid] = lpb;
        // consumed as blA at diagonal d = (t+1)+u, slot u
        bl_diag[((size_t)b * DROWS + (t + 1 + u)) * SD + u] = lpb;
    }
    if (u < U_DIM) {
        int lab = labels[b * U_DIM + u];             // 0..127
        if (hl == (lab >> 2)) {
            int r = lab & 3;
            float v = (r == 0) ? x.x : (r == 1) ? x.y : (r == 2) ? x.z : x.w;
            float lpe = v - lse;
            // emit(t,u) consumed as emC at diagonal d = t+(u+1), slot u+1
            em_diag[((size_t)b * DROWS + (t + u + 1)) * SD + (u + 1)] = lpe;
        }
    }
}

// Kernel 2: anti-diagonal DP, ONE wave per batch, zero barriers.
// Lane l holds cells u=l (slot0) and u=64+l (slot1); neighbor via shuffles.
// Operands register-prefetched 8 diagonals ahead (all static indices).
__global__ __launch_bounds__(64) void dp_kernel(
    const float* __restrict__ bl_diag, const float* __restrict__ em_diag,
    const float* __restrict__ blank_row,
    const int* __restrict__ act_lens, const int* __restrict__ label_lens,
    float* __restrict__ loglike)
{
    const int b = blockIdx.x;
    const int l = threadIdx.x;                  // 0..63
    const float* BD = bl_diag + (size_t)b * DROWS * SD;
    const float* ED = em_diag + (size_t)b * DROWS * SD;
    const int tl = act_lens[b] - 1;
    const int ul = label_lens[b];
    const int dfin = tl + ul;                   // in [177, 355]

    const float NEG = -INFINITY;
    const int u0 = l, u1 = 64 + l;

    float v0 = (l == 0) ? 0.0f : NEG;           // diagonal d=0: alpha[0,0]=0
    float v1 = NEG;
    float res = NEG;

    // prime prefetch for diagonals 1..8
    float cA0[8], cA1[8], cC0[8], cC1[8];
    #pragma unroll
    for (int k = 0; k < 8; ++k) {
        cA0[k] = BD[(size_t)(1 + k) * SD + u0];
        cA1[k] = BD[(size_t)(1 + k) * SD + u1];
        cC0[k] = ED[(size_t)(1 + k) * SD + u0];
        cC1[k] = ED[(size_t)(1 + k) * SD + u1];
    }

    for (int d = 1; d <= 353; d += 8) {         // covers d+k in [1,360]; 356+ fully masked
        float nA0[8], nA1[8], nC0[8], nC1[8];
        #pragma unroll
        for (int k = 0; k < 8; ++k) {           // prefetch diagonals d+8..d+15
            nA0[k] = BD[(size_t)(d + 8 + k) * SD + u0];
            nA1[k] = BD[(size_t)(d + 8 + k) * SD + u1];
            nC0[k] = ED[(size_t)(d + 8 + k) * SD + u0];
            nC1[k] = ED[(size_t)(d + 8 + k) * SD + u1];
        }
        #pragma unroll
        for (int k = 0; k < 8; ++k) {
            const int dd = d + k;
            // neighbors alpha[t,u-1] from previous diagonal
            float p0  = __shfl_up(v0, 1);
            float p1  = __shfl_up(v1, 1);
            float x63 = __shfl(v0, 63);
            float left0 = (l == 0) ? NEG : p0;          // dprev[u0-1] (u0=0 masked below)
            float left1 = (l == 0) ? x63 : p1;          // dprev[u1-1]

            int t0 = dd - u0, t1 = dd - u1;
            bool val0 = (t0 >= 0) && (t0 <= T_DIM - 1);                   // u0<=63<=100
            bool val1 = (u1 <= U_DIM) && (t1 >= 0) && (t1 <= T_DIM - 1);

            float bA0 = (val0 && t0 >= 1) ? cA0[k] : NEG;
            float eC0 = (val0 && u0 >= 1) ? cC0[k] : NEG;
            float bA1 = (val1 && t1 >= 1) ? cA1[k] : NEG;
            float eC1 =  val1             ? cC1[k] : NEG;   // u1>=64>=1 always

            float n0 = logadd(v0 + bA0, left0 + eC0);
            float n1 = logadd(v1 + bA1, left1 + eC1);
            if (!val0) n0 = NEG;
            if (!val1) n1 = NEG;

            if (dd == dfin) {                    // capture alpha[tl, ul]
                if (u0 == ul) res = n0;
                if (u1 == ul) res = n1;
            }
            v0 = n0; v1 = n1;
        }
        #pragma unroll
        for (int k = 0; k < 8; ++k) {
            cA0[k] = nA0[k]; cA1[k] = nA1[k]; cC0[k] = nC0[k]; cC1[k] = nC1[k];
        }
    }

    // lane holding (ul) writes loglike[b] = alpha[tl,ul] + blank[tl,ul]
    int lane_ul = ul & 63;
    bool in_slot0 = (ul < 64);
    if ((in_slot0 && l == ul) || (!in_slot0 && l == lane_ul)) {
        loglike[b] = res + blank_row[((size_t)b * T_DIM + tl) * U1_DIM + ul];
    }
}

// Kernel 3: deterministic fixed-order reduction of the 8 per-batch loglikes.
__global__ void finalize_kernel(const float* __restrict__ loglike, float* __restrict__ out) {
    if (threadIdx.x == 0 && blockIdx.x == 0) {
        float s = 0.0f;
        #pragma unroll
        for (int i = 0; i < B_DIM; ++i) s += loglike[i];
        out[0] = -s / (float)B_DIM;
    }
}

extern "C" void kernel_launch(void* const* d_in, const int* in_sizes, int n_in,
                              void* d_out, int out_size, void* d_ws, size_t ws_size,
                              hipStream_t stream) {
    const float* acts       = (const float*)d_in[0];
    const int*   labels     = (const int*)d_in[1];
    const int*   act_lens   = (const int*)d_in[2];
    const int*   label_lens = (const int*)d_in[3];

    float* ws        = (float*)d_ws;
    float* blank_row = ws;                                    // B*T*U1
    float* bl_diag   = blank_row + B_DIM * T_DIM * U1_DIM;    // B*DROWS*SD
    float* em_diag   = bl_diag + (size_t)B_DIM * DROWS * SD;  // B*DROWS*SD
    float* loglike   = em_diag + (size_t)B_DIM * DROWS * SD;  // B

    int nrows   = B_DIM * T_DIM * U1_DIM;                     // 206,848
    int nblocks = (nrows + 7) / 8;                            // 8 rows per block

    lsm_kernel<<<nblocks, 256, 0, stream>>>(acts, labels, blank_row, bl_diag, em_diag, nrows);
    dp_kernel<<<B_DIM, 64, 0, stream>>>(bl_diag, em_diag, blank_row, act_lens, label_lens, loglike);
    finalize_kernel<<<1, 64, 0, stream>>>(loglike, (float*)d_out);
}

// Round 3
// 73.424 us; speedup vs baseline: 3.8465x; 1.5099x over previous
//
#include <hip/hip_runtime.h>
#include <math.h>

// Problem shape (fixed by the reference setup_inputs):
#define B_DIM  8
#define T_DIM  256
#define U_DIM  100
#define U1_DIM 101
#define V_DIM  128

// Diagonal-major operand arrays: [b][d][u], row stride SD floats.
// Lane l of the DP wave owns u = 2l, 2l+1  (covers u=0..127 >= 101).
#define SD     128
#define DROWS  372   // max written d = 356; max prefetched row = 368

#define NEGF  (-1.0e30f)

// finite-arithmetic logaddexp (operands are >= -4e32, never inf/nan)
__device__ __forceinline__ float logadd(float a, float b) {
    float m = fmaxf(a, b);
    float n = fminf(a, b);
    return m + __logf(1.0f + __expf(n - m));
}

// Kernel 0: fill both diag operand arrays (contiguous) with NEGF.
__global__ __launch_bounds__(256) void fill_kernel(float4* __restrict__ p, int n4) {
    int i = blockIdx.x * 256 + threadIdx.x;
    if (i < n4) p[i] = make_float4(NEGF, NEGF, NEGF, NEGF);
}

// Kernel 1: log-softmax over V=128 per (b,t,u) row.
// One 32-lane half-wave per row, float4 per lane (16B/lane, 1KB/wave-load).
__global__ __launch_bounds__(256) void lsm_kernel(
    const float* __restrict__ acts, const int* __restrict__ labels,
    float* __restrict__ blank_row, float* __restrict__ bl_diag,
    float* __restrict__ em_diag, int nrows)
{
    int rid = blockIdx.x * 8 + (threadIdx.x >> 5);   // 8 rows per 256-thr block
    if (rid >= nrows) return;
    int hl = threadIdx.x & 31;                        // lane within 32-half

    const float* row = acts + (size_t)rid * V_DIM;
    float4 x = *reinterpret_cast<const float4*>(row + 4 * hl);

    float m = fmaxf(fmaxf(x.x, x.y), fmaxf(x.z, x.w));
    #pragma unroll
    for (int off = 16; off; off >>= 1) m = fmaxf(m, __shfl_xor(m, off));
    float s = __expf(x.x - m) + __expf(x.y - m) + __expf(x.z - m) + __expf(x.w - m);
    #pragma unroll
    for (int off = 16; off; off >>= 1) s += __shfl_xor(s, off);
    float lse = m + __logf(s);

    int u  = rid % U1_DIM;
    int bt = rid / U1_DIM;          // b*T + t
    int b  = bt / T_DIM;
    int t  = bt - b * T_DIM;

    if (hl == 0) {
        float lpb = x.x - lse;                       // BLANK = vocab element 0
        blank_row[rid] = lpb;
        // consumed as blank-arrival operand at diagonal d = (t+1)+u, slot u
        bl_diag[((size_t)b * DROWS + (t + 1 + u)) * SD + u] = lpb;
    }
    if (u < U_DIM) {
        int lab = labels[b * U_DIM + u];             // 0..127
        if (hl == (lab >> 2)) {
            int r = lab & 3;
            float v = (r == 0) ? x.x : (r == 1) ? x.y : (r == 2) ? x.z : x.w;
            // emit(t,u) consumed as emit-arrival operand at d = t+(u+1), slot u+1
            em_diag[((size_t)b * DROWS + (t + u + 1)) * SD + (u + 1)] = v - lse;
        }
    }
}

// Kernel 2: anti-diagonal DP, ONE wave per batch, zero barriers, one shfl/diag.
// Lane l owns u=2l (v0) and u=2l+1 (v1). v1's left neighbor is in-lane (v0);
// only v0 needs prev lane's v1 via shfl_up. No masking: gaps pre-filled NEGF.
__global__ __launch_bounds__(64, 1) void dp_kernel(
    const float* __restrict__ bl_diag, const float* __restrict__ em_diag,
    const float* __restrict__ blank_row,
    const int* __restrict__ act_lens, const int* __restrict__ label_lens,
    float* __restrict__ loglike)
{
    const int b = blockIdx.x;
    const int l = threadIdx.x;                  // 0..63
    const float* BD = bl_diag + (size_t)b * DROWS * SD + 2 * l;
    const float* ED = em_diag + (size_t)b * DROWS * SD + 2 * l;
    const int tl = act_lens[b] - 1;
    const int ul = label_lens[b];
    const int dfin = tl + ul;                   // in [177, 355]

    float v0 = (l == 0) ? 0.0f : NEGF;          // diagonal d=0: alpha[0,0]=0
    float v1 = NEGF;

    // prime operands for diagonals 1..16
    float2 cB[16], cE[16];
    #pragma unroll
    for (int k = 0; k < 16; ++k) {
        cB[k] = *(const float2*)(BD + (size_t)(1 + k) * SD);
        cE[k] = *(const float2*)(ED + (size_t)(1 + k) * SD);
    }

    const int nfull = dfin >> 4;     // 16-diag blocks: block j covers [16j+1, 16j+16]
    for (int j = 0; j < nfull; ++j) {
        const int dnext = 16 * (j + 1) + 1;
        float2 nB[16], nE[16];
        #pragma unroll
        for (int k = 0; k < 16; ++k) {          // prefetch next 16 diagonals
            nB[k] = *(const float2*)(BD + (size_t)(dnext + k) * SD);
            nE[k] = *(const float2*)(ED + (size_t)(dnext + k) * SD);
        }
        #pragma unroll
        for (int k = 0; k < 16; ++k) {
            float left0 = __shfl_up(v1, 1);     // prev diag u=2l-1 (lane0: dead path)
            float a0 = v0 + cB[k].x;            // blank arrival, u=2l
            float b0 = left0 + cE[k].x;         // emit arrival,  u=2l
            float a1 = v1 + cB[k].y;            // blank arrival, u=2l+1
            float b1 = v0 + cE[k].y;            // emit arrival (in-lane), u=2l+1
            v0 = logadd(a0, b0);
            v1 = logadd(a1, b1);
        }
        #pragma unroll
        for (int k = 0; k < 16; ++k) { cB[k] = nB[k]; cE[k] = nE[k]; }
    }
    // remainder diagonals 16*nfull+1 .. dfin (<16), operands already in cB/cE
    {
        const int base = 16 * nfull + 1;
        #pragma unroll
        for (int k = 0; k < 16; ++k) {
            if (base + k <= dfin) {             // wave-uniform condition
                float left0 = __shfl_up(v1, 1);
                float a0 = v0 + cB[k].x;
                float b0 = left0 + cE[k].x;
                float a1 = v1 + cB[k].y;
                float b1 = v0 + cE[k].y;
                v0 = logadd(a0, b0);
                v1 = logadd(a1, b1);
            }
        }
    }

    float res = (ul & 1) ? v1 : v0;             // alpha[tl, ul] lives in lane ul>>1
    if (l == (ul >> 1)) {
        loglike[b] = res + blank_row[((size_t)b * T_DIM + tl) * U1_DIM + ul];
    }
}

// Kernel 3: deterministic fixed-order reduction of the 8 per-batch loglikes.
__global__ void finalize_kernel(const float* __restrict__ loglike, float* __restrict__ out) {
    if (threadIdx.x == 0 && blockIdx.x == 0) {
        float s = 0.0f;
        #pragma unroll
        for (int i = 0; i < B_DIM; ++i) s += loglike[i];
        out[0] = -s / (float)B_DIM;
    }
}

extern "C" void kernel_launch(void* const* d_in, const int* in_sizes, int n_in,
                              void* d_out, int out_size, void* d_ws, size_t ws_size,
                              hipStream_t stream) {
    const float* acts       = (const float*)d_in[0];
    const int*   labels     = (const int*)d_in[1];
    const int*   act_lens   = (const int*)d_in[2];
    const int*   label_lens = (const int*)d_in[3];

    float* ws        = (float*)d_ws;
    float* blank_row = ws;                                    // B*T*U1
    float* bl_diag   = blank_row + B_DIM * T_DIM * U1_DIM;    // B*DROWS*SD
    float* em_diag   = bl_diag + (size_t)B_DIM * DROWS * SD;  // B*DROWS*SD (contiguous)
    float* loglike   = em_diag + (size_t)B_DIM * DROWS * SD;  // B

    int nrows   = B_DIM * T_DIM * U1_DIM;                     // 206,848
    int nblocks = (nrows + 7) / 8;                            // 8 rows per block

    int nfill4  = (2 * B_DIM * DROWS * SD) / 4;               // both diag arrays
    fill_kernel<<<(nfill4 + 255) / 256, 256, 0, stream>>>((float4*)bl_diag, nfill4);
    lsm_kernel<<<nblocks, 256, 0, stream>>>(acts, labels, blank_row, bl_diag, em_diag, nrows);
    dp_kernel<<<B_DIM, 64, 0, stream>>>(bl_diag, em_diag, blank_row, act_lens, label_lens, loglike);
    finalize_kernel<<<1, 64, 0, stream>>>(loglike, (float*)d_out);
}